// Round 7
// baseline (295.967 us; speedup 1.0000x reference)
//
#include <hip/hip_runtime.h>
#include <stdint.h>

// x: (32, 256, 58, 58) f32 binary {0,1};  w: (256, 256, 3, 3) f32
// out: (32, 256, 56, 56) f32 = alpha[o]*(2S - 2304), S = XNOR matches
// out = fma(-2*alpha[o], P, 2304*alpha[o]),  P = popcount(xbits ^ wbits)

#define BATCH 32
#define C_IN 256
#define OCH 256
#define HIN 58
#define WIN2 58
#define HOUT 56
#define WOUT 56
#define TAPS 9
#define WWORDS 8            // 256 channels / 32 bits
#define HWIN (HIN * WIN2)   // 3364
#define HWOUT (HOUT * WOUT) // 3136
#define NPOS (BATCH * HWIN) // 107648

typedef unsigned int u32x8 __attribute__((ext_vector_type(8)));

// Fused xor + accumulate-popcount; weight operand pinned to ARCH VGPR class
// ("v"; AGPRs are "a"), window word from SGPR (v_xor src0=SGPR legal).
#define XA0(xs, wv) { uint32_t _t;                                        \
    asm("v_xor_b32 %0, %2, %3\n\tv_bcnt_u32_b32 %1, %0, %1"               \
        : "=&v"(_t), "+v"(a0) : "s"(xs), "v"(wv)); }
#define XA1(xs, wv) { uint32_t _t;                                        \
    asm("v_xor_b32 %0, %2, %3\n\tv_bcnt_u32_b32 %1, %0, %1"               \
        : "=&v"(_t), "+v"(a1) : "s"(xs), "v"(wv)); }

// ---------------------------------------------------------------------------
// Kernel 1: bit-pack x along channels. Thread ↔ (position p, word-pair wp).
// Reads 64B-coalesced per (wp,j) group; writes fully contiguous uint2/wave.
// ---------------------------------------------------------------------------
__global__ __launch_bounds__(256) void pack_x_kernel(
    const float* __restrict__ x, uint32_t* __restrict__ xp)
{
    int t = blockIdx.x * 256 + threadIdx.x;      // 1682 blocks exactly
    int p  = t >> 2;                             // position in [0, NPOS)
    int wp = t & 3;                              // word pair
    int b = p / HWIN;
    int r = p - b * HWIN;
    const float* xb = x + ((size_t)(b * C_IN + wp * 64)) * HWIN + r;
    uint32_t m0 = 0u, m1 = 0u;
    #pragma unroll
    for (int j = 0; j < 32; ++j) {
        float v0 = xb[(size_t)j * HWIN];
        float v1 = xb[(size_t)(j + 32) * HWIN];
        m0 |= (v0 > 0.5f ? 1u : 0u) << j;        // word 2wp,   bit j = ch 64wp+j
        m1 |= (v1 > 0.5f ? 1u : 0u) << j;        // word 2wp+1, bit j = ch 64wp+32+j
    }
    *(uint2*)(xp + (size_t)p * WWORDS + wp * 2) = make_uint2(m0, m1);
}

// ---------------------------------------------------------------------------
// Kernel 2: pack weights O-MINOR: wq[(tap*8 + word)*256 + o] so the main
// kernel's per-lane (lane = o) weight loads are stride-1 coalesced.
// Also per-o scale/bias.
// ---------------------------------------------------------------------------
__global__ __launch_bounds__(256) void pack_w_kernel(
    const float* __restrict__ wt, uint32_t* __restrict__ wq,
    float* __restrict__ sA, float* __restrict__ sB)
{
    int o = blockIdx.x;
    int c = threadIdx.x;
    const float* wb = wt + ((size_t)o * C_IN + c) * TAPS;
    float wv[TAPS];
    float s = 0.f;
    #pragma unroll
    for (int t = 0; t < TAPS; ++t) {
        wv[t] = wb[t];
        s += fabsf(wv[t]);
    }
    int wave = c >> 6, lane = c & 63;
    #pragma unroll
    for (int t = 0; t < TAPS; ++t) {
        unsigned long long m = __ballot(wv[t] >= 0.0f);
        if (lane == 0) {
            // word index w2 = wave*2 holds channels wave*64..+31 (bit j = ch)
            wq[(size_t)(t * 8 + wave * 2)     * OCH + o] = (uint32_t)m;
            wq[(size_t)(t * 8 + wave * 2 + 1) * OCH + o] = (uint32_t)(m >> 32);
        }
    }
    __shared__ float red[256];
    red[c] = s;
    __syncthreads();
    for (int off = 128; off > 0; off >>= 1) {
        if (c < off) red[c] += red[c + off];
        __syncthreads();
    }
    if (c == 0) {
        float alpha = red[0] / (float)(C_IN * HWIN);   // n = C*H*W per reference
        sA[o] = -2.0f * alpha;
        sB[o] = (float)(C_IN * TAPS) * alpha;          // 2304 * alpha
    }
}

// ---------------------------------------------------------------------------
// Kernel 3: main — lane = output channel; weights forced into ARCH VGPRs.
// R10 A/B vs R6: ONLY change is amdgpu_waves_per_eu(4,4) (min AND max).
// R6 post-mortem: VGPR_Count=40 persisted -> wreg[72] still AGPR-homed and
// the "v" asm constraints forced one v_accvgpr_read per use: 222 VALU/pos
// x 2cyc x 14 pos x 28 waves/SIMD = 174k cyc/SIMD = 111us @1.57GHz
// sustained ~= measured 106.7. Root cause: __launch_bounds__(256,4) sets
// only a MIN waves/EU; the allocator still chases higher occupancy, caps
// arch VGPRs ~40, and shunts the live-through array to AGPRs — paying the
// copies while total regs (112) pin us to 4 waves anyway. Pinning max=4
// removes the incentive: arch budget 128, wreg stays "v"-class (every use
// demands "v"), copies vanish -> 150 VALU/pos. Witness: VGPR_Count >= 96.
// Structure unchanged: block = 64 o (grid.y of 4) x one output row (b,oy);
// wave w owns positions [14w,14w+14); x-window wave-uniform in 72 SGPRs via
// s_load_dwordx8, reloaded per position (SMEM only, hidden under VALU);
// store staged in LDS [64][57] then flushed coalesced.
// Tail note: the last position's pipelined reload reads 32B past xp's end —
// lands in wq (same workspace, allocated), values never consumed.
// ---------------------------------------------------------------------------
__global__ __launch_bounds__(256)
__attribute__((amdgpu_waves_per_eu(4, 4)))
void xnor_main_kernel(
    const uint32_t* __restrict__ xp, const uint32_t* __restrict__ wq,
    const float* __restrict__ sA, const float* __restrict__ sB,
    float* __restrict__ out)
{
    __shared__ float olds[64 * 57];              // 14,592 B

    int rj = blockIdx.x;                         // row-job 0..1791
    int b  = rj / HOUT;
    int oy = rj - b * HOUT;
    int obase = blockIdx.y * 64;
    int lane = threadIdx.x & 63;
    int wv_id = __builtin_amdgcn_readfirstlane((int)(threadIdx.x >> 6));
    int o = obase + lane;

    // Weights resident in VGPRs: 72 dwords per lane, coalesced stride-1.
    uint32_t wreg[72];
    #pragma unroll
    for (int i = 0; i < 72; ++i)
        wreg[i] = wq[(size_t)i * OCH + o];
    float sAv = sA[o];
    float sBv = sB[o];

    int ox0 = wv_id * 14;                        // this wave's first position

    // Wave-uniform row pointers (all factors uniform -> s_load path).
    const uint32_t* r0 = xp + (((size_t)b * HIN + oy + 0) * WIN2 + ox0) * WWORDS;
    const uint32_t* r1 = xp + (((size_t)b * HIN + oy + 1) * WIN2 + ox0) * WWORDS;
    const uint32_t* r2 = xp + (((size_t)b * HIN + oy + 2) * WIN2 + ox0) * WWORDS;

    // Window: rows 0..2 x cols dx=0..2, 8 words each (72 SGPRs).
    u32x8 W0a = *(const u32x8*)(r0);
    u32x8 W0b = *(const u32x8*)(r0 + 8);
    u32x8 W0c = *(const u32x8*)(r0 + 16);
    u32x8 W1a = *(const u32x8*)(r1);
    u32x8 W1b = *(const u32x8*)(r1 + 8);
    u32x8 W1c = *(const u32x8*)(r1 + 16);
    u32x8 W2a = *(const u32x8*)(r2);
    u32x8 W2b = *(const u32x8*)(r2 + 8);
    u32x8 W2c = *(const u32x8*)(r2 + 16);

    #pragma unroll 1
    for (int i = 0; i < 14; ++i) {
        uint32_t a0 = 0u, a1 = 0u;
        // ---- row 0: taps 0,1,2 ---- consume, then reload for pos+1
        #pragma unroll
        for (int k = 0; k < 8; ++k) XA0(W0a[k], wreg[0 * 8 + k]);
        #pragma unroll
        for (int k = 0; k < 8; ++k) XA1(W0b[k], wreg[1 * 8 + k]);
        #pragma unroll
        for (int k = 0; k < 8; ++k) XA0(W0c[k], wreg[2 * 8 + k]);
        r0 += 8;
        W0a = *(const u32x8*)(r0);
        W0b = *(const u32x8*)(r0 + 8);
        W0c = *(const u32x8*)(r0 + 16);
        // ---- row 1: taps 3,4,5 ----
        #pragma unroll
        for (int k = 0; k < 8; ++k) XA1(W1a[k], wreg[3 * 8 + k]);
        #pragma unroll
        for (int k = 0; k < 8; ++k) XA0(W1b[k], wreg[4 * 8 + k]);
        #pragma unroll
        for (int k = 0; k < 8; ++k) XA1(W1c[k], wreg[5 * 8 + k]);
        r1 += 8;
        W1a = *(const u32x8*)(r1);
        W1b = *(const u32x8*)(r1 + 8);
        W1c = *(const u32x8*)(r1 + 16);
        // ---- row 2: taps 6,7,8 ----
        #pragma unroll
        for (int k = 0; k < 8; ++k) XA0(W2a[k], wreg[6 * 8 + k]);
        #pragma unroll
        for (int k = 0; k < 8; ++k) XA1(W2b[k], wreg[7 * 8 + k]);
        #pragma unroll
        for (int k = 0; k < 8; ++k) XA0(W2c[k], wreg[8 * 8 + k]);
        r2 += 8;
        W2a = *(const u32x8*)(r2);
        W2b = *(const u32x8*)(r2 + 8);
        W2c = *(const u32x8*)(r2 + 16);

        float P = (float)(a0 + a1);
        olds[lane * 57 + (ox0 + i)] = fmaf(sAv, P, sBv);
    }

    __syncthreads();

    // Coalesced flush: 64 o-rows x 56 positions = 3584 f32 by 256 threads.
    size_t obb = ((size_t)b * OCH + obase) * HWOUT + (size_t)oy * WOUT;
    int tau = threadIdx.x;
    #pragma unroll 1
    for (int i = 0; i < 14; ++i) {
        int flat = i * 256 + tau;                // 0..3583
        int op = flat / 56;
        int pp = flat - op * 56;
        out[obb + (size_t)op * HWOUT + pp] = olds[op * 57 + pp];
    }
}

// ---------------------------------------------------------------------------
extern "C" void kernel_launch(void* const* d_in, const int* in_sizes, int n_in,
                              void* d_out, int out_size, void* d_ws, size_t ws_size,
                              hipStream_t stream)
{
    const float* x  = (const float*)d_in[0];
    const float* wt = (const float*)d_in[1];
    float* out = (float*)d_out;

    char* ws = (char*)d_ws;
    uint32_t* xp = (uint32_t*)ws;                               // 3,444,736 B
    uint32_t* wq = (uint32_t*)(ws + 3444736);                   //    73,728 B
    float*    sA = (float*)(ws + 3444736 + 73728);              //     1,024 B
    float*    sB = (float*)(ws + 3444736 + 73728 + 1024);       //     1,024 B

    // 1) pack x: 430,592 threads / 256 = 1682 blocks exactly
    pack_x_kernel<<<dim3(1682), dim3(256), 0, stream>>>(x, xp);

    // 2) pack weights (o-minor) + scales
    pack_w_kernel<<<dim3(OCH), dim3(256), 0, stream>>>(wt, wq, sA, sB);

    // 3) main: 1792 row-jobs x 4 o-groups of 64
    xnor_main_kernel<<<dim3(1792, 4), dim3(256), 0, stream>>>(xp, wq, sA, sB, out);
}